// Round 19
// baseline (66.297 us; speedup 1.0000x reference)
//
#include <hip/hip_runtime.h>
#include <float.h>

// VectorQuantizer on MI355X — MFMA f16 screen + compacted np-f32 rescue,
// 2-tile software pipeline per block, loss folded in via last-block reduction.
//
// R15-R18 plateau (48/44.5/45.9/43.3us): all pipes <16%, occupancy ~12 waves/CU
// in EVERY config -> dispatch/drain ramp of 1024 short blocks + 3-launch serial
// tail dominate. R19: (1) 512 blocks x 2 tiles, tile i+1's x-loads issued to
// regs during tile i's compute (reg loads stay in flight across s_barrier;
// m97's vmcnt-drain applies only to global_load_lds); (2) vq_loss merged into
// vq_main (last-block-done, deterministic fixed-order reduce, device-scope
// atomics per G16); (3) per-tile numerics byte-identical to R18 (passed).
#pragma clang fp contract(off)

#define K_EMB   512
#define D_EMB   64
#define Q_ELEMS 4194304   // 64 * 64 * 32 * 32
#define TPB     2         // tiles per block
#define NBLK    512       // 1024 tiles / TPB
#define W_SCR   0.5f      // rescue window, scaled (512x) — validated R13-R18
#define XROW    65        // xf row stride (odd -> bank-spread)
#define LCAP    1024      // candidate list capacity (avg ~77/tile)

typedef _Float16 f16x8 __attribute__((ext_vector_type(8)));
typedef _Float16 f16x2 __attribute__((ext_vector_type(2)));
typedef float    f32x4 __attribute__((ext_vector_type(4)));

// numpy pairwise_sum order for n=64 contiguous f32, summing PRE-ROUNDED squares.
__device__ __forceinline__ float np_sumsq64(const float* v) {
    float r[8];
    #pragma unroll
    for (int j = 0; j < 8; ++j) r[j] = v[j] * v[j];
    #pragma unroll
    for (int i = 8; i < 64; i += 8) {
        #pragma unroll
        for (int j = 0; j < 8; ++j) {
            float s = v[i + j] * v[i + j];
            r[j] = r[j] + s;
        }
    }
    return ((r[0] + r[1]) + (r[2] + r[3])) + ((r[4] + r[5]) + (r[6] + r[7]));
}

// ---------------- kernel 1: t2, 512*t2, A-fragment table, zero done-counter ----
__global__ __launch_bounds__(256) void vq_prep(const float* __restrict__ emb,
                                               float* __restrict__ t2,
                                               float* __restrict__ t2s512,
                                               f16x8* __restrict__ embA,
                                               unsigned int* __restrict__ done) {
    const int g = blockIdx.x * 256 + threadIdx.x;
    if (g == 0) *done = 0u;
    if (g < K_EMB) {
        const float* ep = emb + (g << 6);
        float s = np_sumsq64(ep);
        t2[g]     = s;
        t2s512[g] = 512.0f * s;
    }
    if (g < 4096) {
        const int t = g >> 7;
        const int s = (g >> 6) & 1;
        const int l = g & 63;
        const int code  = t * 16 + (l & 15);
        const int dbase = s * 32 + ((l >> 4) << 3);
        const float* ep = emb + (code << 6) + dbase;
        f16x8 a;
        #pragma unroll
        for (int i = 0; i < 8; ++i) a[i] = (_Float16)(512.0f * ep[i]);
        embA[g] = a;
    }
}

// ---------------- kernel 2: main VQ (pipelined 2 tiles / block) ----------------
__global__ __launch_bounds__(512) void vq_main(const float* __restrict__ x,
                                               const float* __restrict__ emb,
                                               const float* __restrict__ t2,
                                               const float* __restrict__ t2s512,
                                               const f16x8* __restrict__ embA,
                                               float* __restrict__ out_q,
                                               float* __restrict__ out_idx,
                                               float* __restrict__ partial,
                                               unsigned int* __restrict__ done,
                                               float* __restrict__ loss) {
    const int tid  = threadIdx.x;
    const int lane = tid & 63;
    const int wave = tid >> 6;                  // 0..7
    const int pt   = wave & 3;                  // pixel-tile (16 pixels)
    const int ch   = wave >> 2;                 // code-half (16 MFMA tiles)
    const int p    = tid & 63;                  // stage/epilogue pixel role

    __shared__ float xf[TPB][64 * XROW];        // 2 x 16.6 KB
    __shared__ float t1s[TPB][64];
    __shared__ float mwv[TPB][8][16];
    __shared__ unsigned long long keys[TPB][64];
    __shared__ int   list[LCAP];                // reused (barrier-separated)
    __shared__ int   lcnt[TPB];
    __shared__ float red[8];
    __shared__ int   lastf;

    // ---- prologue: stage tile 0, init its control state ----
    {
        const int n0 = (blockIdx.x * TPB) * 64 + p;
        const float* __restrict__ xs = x + (n0 >> 10) * 65536 + (n0 & 1023);
        #pragma unroll
        for (int j = 0; j < 8; ++j)
            xf[0][p * XROW + wave * 8 + j] = xs[(wave * 8 + j) * 1024];
        if (tid < 64) keys[0][tid] = 0xFFFFFFFFFFFFFFFFull;
        if (tid == 0) lcnt[0] = 0;
    }
    __syncthreads();

    const f32x4 czero = {0.f, 0.f, 0.f, 0.f};
    const float4* __restrict__ t2s4 = (const float4*)t2s512;
    const int t0 = ch * 16;
    const int bp = 16 * pt + (lane & 15);
    const int bg = lane >> 4;

    float accLoss = 0.f;

    #pragma unroll
    for (int it = 0; it < TPB; ++it) {
        const int ti = blockIdx.x * TPB + it;

        // issue next tile's stage loads EARLY (regs; in flight across barriers)
        float rv[8];
        if (it + 1 < TPB) {
            const int n1 = (ti + 1) * 64 + p;
            const float* __restrict__ xs1 = x + (n1 >> 10) * 65536 + (n1 & 1023);
            #pragma unroll
            for (int j = 0; j < 8; ++j) rv[j] = xs1[(wave * 8 + j) * 1024];
        }

        // wave 0: np-exact t1 for this tile (consumed after B2, in rescue)
        if (wave == 0) t1s[it][lane] = np_sumsq64(&xf[it][lane * XROW]);

        // B-fragments (RN f16 cvt from LDS f32)
        f16x8 b0, b1;
        #pragma unroll
        for (int i = 0; i < 8; ++i) {
            b0[i] = (_Float16)xf[it][bp * XROW + 0 * 32 + bg * 8 + i];
            b1[i] = (_Float16)xf[it][bp * XROW + 1 * 32 + bg * 8 + i];
        }

        // ---- pass 1: MFMA screen, pack dists to f16 regs, track min ----
        f16x2 hv[32];
        float m = FLT_MAX;
        #pragma unroll
        for (int tt = 0; tt < 16; ++tt) {
            const int t = t0 + tt;
            f16x8 a0 = embA[(t * 2 + 0) * 64 + lane];
            f16x8 a1 = embA[(t * 2 + 1) * 64 + lane];
            f32x4 c = __builtin_amdgcn_mfma_f32_16x16x32_f16(a0, b0, czero, 0, 0, 0);
            c = __builtin_amdgcn_mfma_f32_16x16x32_f16(a1, b1, c, 0, 0, 0);
            float4 tv = t2s4[t * 4 + bg];
            float s0 = fmaf(-2.f, c[0], tv.x);
            float s1 = fmaf(-2.f, c[1], tv.y);
            float s2 = fmaf(-2.f, c[2], tv.z);
            float s3 = fmaf(-2.f, c[3], tv.w);
            f16x2 p01, p23;
            p01[0] = (_Float16)s0; p01[1] = (_Float16)s1;
            p23[0] = (_Float16)s2; p23[1] = (_Float16)s3;
            hv[tt * 2 + 0] = p01;
            hv[tt * 2 + 1] = p23;
            m = fminf(m, fminf(fminf(s0, s1), fminf(s2, s3)));
        }
        m = fminf(m, __shfl_xor(m, 16));
        m = fminf(m, __shfl_xor(m, 32));
        if (lane < 16) mwv[it][wave][lane] = m;
        __syncthreads();                                        // B1

        const float thr = fminf(mwv[it][pt][lane & 15],
                                mwv[it][pt + 4][lane & 15]) + W_SCR;

        // ---- pass 2: register scan, collect candidates ----
        #pragma unroll
        for (int tt = 0; tt < 16; ++tt) {
            f16x2 p01 = hv[tt * 2 + 0];
            f16x2 p23 = hv[tt * 2 + 1];
            float s0 = (float)p01[0];
            float s1 = (float)p01[1];
            float s2 = (float)p23[0];
            float s3 = (float)p23[1];
            const int kb = (t0 + tt) * 16 + bg * 4;
            if (s0 < thr) { int s = atomicAdd(&lcnt[it], 1); if (s < LCAP) list[s] = bp * 512 + kb + 0; }
            if (s1 < thr) { int s = atomicAdd(&lcnt[it], 1); if (s < LCAP) list[s] = bp * 512 + kb + 1; }
            if (s2 < thr) { int s = atomicAdd(&lcnt[it], 1); if (s < LCAP) list[s] = bp * 512 + kb + 2; }
            if (s3 < thr) { int s = atomicAdd(&lcnt[it], 1); if (s < LCAP) list[s] = bp * 512 + kb + 3; }
        }
        __syncthreads();                                        // B2

        // ---- rescue: exact np-f32, one candidate per lane ----
        const int ncand = min(lcnt[it], LCAP);
        for (int i = tid; i < ncand; i += 512) {
            const int v  = list[i];
            const int pp = v >> 9;
            const int k  = v & 511;
            const float* xp = &xf[it][pp * XROW];
            const float* __restrict__ ep = emb + (k << 6);
            float a = 0.f;
            #pragma unroll
            for (int d = 0; d < D_EMB; ++d) a = fmaf(xp[d], ep[d], a);
            float X = t1s[it][pp] + t2[k];
            float dnp = fmaf(-2.f, a, X);
            unsigned long long key =
                ((unsigned long long)__float_as_uint(dnp) << 32) | (unsigned)k;
            atomicMin(&keys[it][pp], key);
        }
        __syncthreads();                                        // B3

        // ---- epilogue for this tile + stage-write for next ----
        {
            const int n2 = ti * 64 + p;
            const int kw = (int)(unsigned)(keys[it][p] & 0xFFFFFFFFull);
            float* __restrict__ qp = out_q + (n2 >> 10) * 65536 + (n2 & 1023);
            const float4* __restrict__ eq =
                (const float4*)(emb + (kw << 6) + wave * 8);
            #pragma unroll
            for (int j4 = 0; j4 < 2; ++j4) {
                float4 qv = eq[j4];
                const int d = wave * 8 + j4 * 4;
                float f0 = qv.x - xf[it][p * XROW + d + 0];
                float f1 = qv.y - xf[it][p * XROW + d + 1];
                float f2 = qv.z - xf[it][p * XROW + d + 2];
                float f3 = qv.w - xf[it][p * XROW + d + 3];
                accLoss = fmaf(f0, f0, accLoss);
                accLoss = fmaf(f1, f1, accLoss);
                accLoss = fmaf(f2, f2, accLoss);
                accLoss = fmaf(f3, f3, accLoss);
                qp[(d + 0) * 1024] = qv.x;
                qp[(d + 1) * 1024] = qv.y;
                qp[(d + 2) * 1024] = qv.z;
                qp[(d + 3) * 1024] = qv.w;
            }
            if (wave == 0) out_idx[n2] = (float)kw;
        }
        if (it + 1 < TPB) {
            #pragma unroll
            for (int j = 0; j < 8; ++j)
                xf[it + 1][p * XROW + wave * 8 + j] = rv[j];
            if (tid < 64) keys[it + 1][tid] = 0xFFFFFFFFFFFFFFFFull;
            if (tid == 0) lcnt[it + 1] = 0;
            __syncthreads();                                    // B4
        }
    }

    // ---- block loss partial ----
    #pragma unroll
    for (int off = 32; off > 0; off >>= 1) accLoss += __shfl_down(accLoss, off);
    if (lane == 0) red[wave] = accLoss;
    __syncthreads();
    if (tid == 0) {
        partial[blockIdx.x] = ((red[0] + red[1]) + (red[2] + red[3]))
                            + ((red[4] + red[5]) + (red[6] + red[7]));
        __threadfence();
        unsigned int old = atomicAdd(done, 1u);
        lastf = (old == NBLK - 1) ? 1 : 0;
    }
    __syncthreads();

    // ---- last block: deterministic loss finalize over 512 partials ----
    if (lastf) {
        __threadfence();
        float v = 0.f;
        if (tid < 256) {
            float a = __hip_atomic_load(&partial[tid], __ATOMIC_RELAXED,
                                        __HIP_MEMORY_SCOPE_AGENT);
            float b = __hip_atomic_load(&partial[tid + 256], __ATOMIC_RELAXED,
                                        __HIP_MEMORY_SCOPE_AGENT);
            v = a + b;
        }
        #pragma unroll
        for (int off = 32; off > 0; off >>= 1) v += __shfl_down(v, off);
        if (lane == 0 && wave < 4) red[wave] = v;
        __syncthreads();
        if (tid == 0)
            loss[0] = 1.25f * ((red[0] + red[1]) + (red[2] + red[3])) / (float)Q_ELEMS;
    }
}

extern "C" void kernel_launch(void* const* d_in, const int* in_sizes, int n_in,
                              void* d_out, int out_size, void* d_ws, size_t ws_size,
                              hipStream_t stream) {
    const float* x   = (const float*)d_in[0];   // [64,64,32,32] NCHW
    const float* emb = (const float*)d_in[1];   // [512,64]

    float* out_q    = (float*)d_out;                // [4194304]
    float* out_loss = (float*)d_out + Q_ELEMS;      // [1]
    float* out_idx  = (float*)d_out + Q_ELEMS + 1;  // [65536] as float

    float*        t2      = (float*)d_ws;           // 512
    float*        t2s512  = t2 + K_EMB;             // 512
    float*        partial = t2s512 + K_EMB;         // 512
    unsigned int* done    = (unsigned int*)(partial + 512);   // 1
    f16x8*        embA    = (f16x8*)((float*)d_ws + 2048);    // 8192B-aligned, 64KB

    vq_prep<<<16, 256, 0, stream>>>(emb, t2, t2s512, embA, done);
    vq_main<<<NBLK, 512, 0, stream>>>(x, emb, t2, t2s512, embA,
                                      out_q, out_idx, partial, done, out_loss);
}